// Round 5
// baseline (413.649 us; speedup 1.0000x reference)
//
#include <hip/hip_runtime.h>

#define NVOX 150000
#define BM 128
#define MTILES 1172         // ceil(150000/128)
#define SROW 150016         // column stride of h buffer
#define NCOL 320

typedef __attribute__((ext_vector_type(8))) short bf16x8;
typedef __attribute__((ext_vector_type(4))) float f32x4;
typedef __attribute__((ext_vector_type(4))) unsigned short us4;

__device__ __forceinline__ unsigned short f2bf(float f) {
    unsigned u = __builtin_bit_cast(unsigned, f);
    u += 0x7fffu + ((u >> 16) & 1u);
    return (unsigned short)(u >> 16);
}

// ---------------- prep: features f32 -> bf16, x8 vectorized (+ zero row) ----------------
__global__ void prep_feat(const float* __restrict__ src, unsigned short* __restrict__ dst) {
    int i = blockIdx.x * 256 + threadIdx.x;
    if (i < NVOX * 8) {
        const float4 a = *(const float4*)(src + (size_t)i * 8);
        const float4 b = *(const float4*)(src + (size_t)i * 8 + 4);
        us4 lo, hi;
        lo.x = f2bf(a.x); lo.y = f2bf(a.y); lo.z = f2bf(a.z); lo.w = f2bf(a.w);
        hi.x = f2bf(b.x); hi.y = f2bf(b.y); hi.z = f2bf(b.z); hi.w = f2bf(b.w);
        *(us4*)(dst + (size_t)i * 8) = lo;
        *(us4*)(dst + (size_t)i * 8 + 4) = hi;
    } else if (i < NVOX * 8 + 8) {
        us4 z; z.x = 0; z.y = 0; z.z = 0; z.w = 0;
        *(us4*)(dst + (size_t)i * 8) = z;   // zero row for invalid/pad gathers
    }
}

// ---- prep: W3[h][kk][c][o] -> Bt[h*64+o][kk*64+c] bf16, LDS tile transpose (coalesced) --
__global__ void prep_w3(const float* __restrict__ w3, unsigned short* __restrict__ bt,
                        float* __restrict__ stats) {
    __shared__ float tile[64 * 65];
    int b = blockIdx.x;            // b = h*9+kk, 45 blocks
    int tid = threadIdx.x;
    const float* src = w3 + (size_t)b * 4096;
#pragma unroll
    for (int t = 0; t < 16; ++t) {
        int lin = t * 256 + tid;   // c = lin>>6, o = lin&63  (coalesced read over o)
        tile[(lin >> 6) * 65 + (lin & 63)] = src[lin];
    }
    __syncthreads();
    int h = b / 9, kk = b - h * 9;
    unsigned short* dst = bt + (size_t)h * 64 * 576 + kk * 64;
#pragma unroll
    for (int t = 0; t < 16; ++t) {
        int lin = t * 256 + tid;   // o = lin>>6, c = lin&63  (coalesced write over c)
        int o = lin >> 6, c = lin & 63;
        dst[(size_t)o * 576 + c] = f2bf(tile[c * 65 + o]);
    }
    if (b == 0) for (int j = tid; j < 2 * NCOL; j += 256) stats[j] = 0.f;
}

// ---------------- gather-GEMM: BM=128/BN=64, wave tile 64x32, manual coalesced row-gather
// (8 lanes span one 128B row -> 2x64B L2 requests), XOR-swizzled LDS, B direct global->reg.
__global__ __launch_bounds__(256, 4)
void gemm_kernel(const unsigned short* __restrict__ featB,
                 const unsigned short* __restrict__ Bt,
                 const int* __restrict__ nbr,
                 unsigned short* __restrict__ hbuf,
                 float* __restrict__ stats) {
    __shared__ __align__(16) char smem[22016];
    constexpr int IDX_OFF = 16384;   // 9*128 int byte-offsets (4608 B); dead after K-loop
    constexpr int SRED_OFF = 20992;  // 4*2*16*2 floats (1024 B)

    // XCD swizzle: the 5 head-blocks of one mtile share bid%8 -> same XCD (A L2 MSHR merge)
    int bid = blockIdx.x;
    int r = bid & 7, q = bid >> 3;
    int ntile = q % 5;
    int mtile = (q / 5) * 8 + r;
    if (mtile >= MTILES) return;
    int m0 = mtile * BM;
    int n0 = ntile * 64;

    int tid = threadIdx.x;
    int w = tid >> 6, lane = tid & 63;
    int quad = lane >> 4, m16 = lane & 15;
    int mrow = (w >> 1) * 64;   // wave's 64-row half
    int ncol = (w & 1) * 32;    // wave's 32-col half

    // ---- stage neighbor byte-offset table: sIdx[kk*128 + row] = srow*128 ----
    for (int lin = tid; lin < 1152; lin += 256) {
        int kkq = lin >> 7, row = lin & 127;
        int v = (m0 + row < NVOX) ? nbr[(size_t)(m0 + row) * 9 + kkq] : -1;
        *(int*)(smem + IDX_OFF + lin * 4) = ((v < 0) ? NVOX : v) * 128;
    }
    __syncthreads();

    f32x4 acc[4][2];
#pragma unroll
    for (int mt = 0; mt < 4; ++mt)
#pragma unroll
        for (int nt = 0; nt < 2; ++nt)
            acc[mt][nt] = (f32x4){0.f, 0.f, 0.f, 0.f};

    const char* fb = (const char*)featB;
    char* sA = smem;                // swizzled row-major: row*128 + (chunk^(row&7))*16
    // staging geometry: thread t handles rows i*32 + (t>>3), chunk c = t&7
    int srow_loc = tid >> 3;        // 0..31
    int schunk = tid & 7;
    int swz_base0 = (srow_loc * 128) + ((schunk ^ (srow_loc & 7)) * 16);

    uint4 av[4];
    // prologue: gather kk=0
#pragma unroll
    for (int i = 0; i < 4; ++i) {
        int off = *(const int*)(smem + IDX_OFF + (0 * 128 + i * 32 + srow_loc) * 4);
        av[i] = *(const uint4*)(fb + off + schunk * 16);
    }

    for (int kk = 0; kk < 9; ++kk) {
        __syncthreads();   // sA consumers (previous iter frags) done
#pragma unroll
        for (int i = 0; i < 4; ++i)
            *(uint4*)(sA + i * 4096 + swz_base0) = av[i];
        __syncthreads();   // sA staged block-wide
        if (kk < 8) {
#pragma unroll
            for (int i = 0; i < 4; ++i) {
                int off = *(const int*)(smem + IDX_OFF + ((kk + 1) * 128 + i * 32 + srow_loc) * 4);
                av[i] = *(const uint4*)(fb + off + schunk * 16);   // overlaps MFMAs below
            }
        }
        // ---- compute: per ks: 4 A ds_read_b128 (swizzle-conflict-free) + 2 B global + 8 MFMA
#pragma unroll
        for (int ks = 0; ks < 2; ++ks) {
            bf16x8 af[4], bf[2];
#pragma unroll
            for (int mt = 0; mt < 4; ++mt) {
                int row = mrow + mt * 16 + m16;
                int chunk = (ks * 4 + quad) ^ (m16 & 7);   // row&7 == m16&7
                af[mt] = *(const bf16x8*)(sA + row * 128 + chunk * 16);
            }
#pragma unroll
            for (int nt = 0; nt < 2; ++nt)
                bf[nt] = *(const bf16x8*)(Bt + (size_t)(n0 + ncol + nt * 16 + m16) * 576 +
                                          kk * 64 + ks * 32 + quad * 8);
#pragma unroll
            for (int mt = 0; mt < 4; ++mt)
#pragma unroll
                for (int nt = 0; nt < 2; ++nt)
                    acc[mt][nt] = __builtin_amdgcn_mfma_f32_16x16x32_bf16(
                        af[mt], bf[nt], acc[mt][nt], 0, 0, 0);
        }
    }

    // ---- epilogue 1: column-major LDS tile (aliases sA+sIdx), coalesced stores ----
    __syncthreads();
    unsigned short* sOut = (unsigned short*)smem;   // 64 cols x 136 ushorts = 17408 B
#pragma unroll
    for (int mt = 0; mt < 4; ++mt) {
#pragma unroll
        for (int nt = 0; nt < 2; ++nt) {
            int col = ncol + nt * 16 + m16;
            int row = mrow + mt * 16 + quad * 4;
            f32x4 v = acc[mt][nt];
            unsigned lo = (unsigned)f2bf(v.x) | ((unsigned)f2bf(v.y) << 16);
            unsigned hi = (unsigned)f2bf(v.z) | ((unsigned)f2bf(v.w) << 16);
            uint2 pk; pk.x = lo; pk.y = hi;
            *(uint2*)(sOut + col * 136 + row) = pk;
        }
    }
    __syncthreads();
#pragma unroll
    for (int it = 0; it < 8; ++it) {
        int col = it * 8 + (tid >> 5);
        int l32 = tid & 31;
        uint2 v = *(const uint2*)(sOut + col * 136 + l32 * 4);
        *(uint2*)(hbuf + (size_t)(n0 + col) * SROW + m0 + l32 * 4) = v;  // 256B runs
    }

    // ---- epilogue 2: BN statistics (pad/invalid rows are exact zeros) ----
    float s[2], ss[2];
#pragma unroll
    for (int nt = 0; nt < 2; ++nt) {
        float a = 0.f, b = 0.f;
#pragma unroll
        for (int mt = 0; mt < 4; ++mt) {
            f32x4 v = acc[mt][nt];
            a += v.x + v.y + v.z + v.w;
            b += v.x * v.x + v.y * v.y + v.z * v.z + v.w * v.w;
        }
        s[nt] = a; ss[nt] = b;
        s[nt] += __shfl_xor(s[nt], 16); s[nt] += __shfl_xor(s[nt], 32);
        ss[nt] += __shfl_xor(ss[nt], 16); ss[nt] += __shfl_xor(ss[nt], 32);
    }
    float* sRed = (float*)(smem + SRED_OFF);
    if (quad == 0) {
#pragma unroll
        for (int nt = 0; nt < 2; ++nt) {
            sRed[((w * 2 + nt) * 16 + m16) * 2 + 0] = s[nt];
            sRed[((w * 2 + nt) * 16 + m16) * 2 + 1] = ss[nt];
        }
    }
    __syncthreads();
    if (tid < 64) {
        int col = tid;
        int half = col >> 5, nt = (col >> 4) & 1, mc = col & 15;
        const float* p0 = (const float*)(smem + SRED_OFF) + ((half * 2 + nt) * 16 + mc) * 2;
        const float* p1 = (const float*)(smem + SRED_OFF) + (((2 + half) * 2 + nt) * 16 + mc) * 2;
        atomicAdd(&stats[n0 + col], p0[0] + p1[0]);
        atomicAdd(&stats[NCOL + n0 + col], p0[1] + p1[1]);
    }
}

// ------- pass 2: BN + ReLU + 1x1 conv; thread = (row-pair, head), h wave-uniform -------
__global__ void head_kernel(const unsigned short* __restrict__ hbuf,
                            const float* __restrict__ stats,
                            const float* __restrict__ gamma, const float* __restrict__ beta,
                            const float* __restrict__ W1_0, const float* __restrict__ W1_1,
                            const float* __restrict__ W1_2, const float* __restrict__ W1_3,
                            const float* __restrict__ W1_4,
                            const float* __restrict__ b1_0, const float* __restrict__ b1_1,
                            const float* __restrict__ b1_2, const float* __restrict__ b1_3,
                            const float* __restrict__ b1_4,
                            float* __restrict__ out) {
    __shared__ float sScale[NCOL], sShift[NCOL], sW1[NCOL * 3], sB1[16];
    int tid = threadIdx.x;
    for (int c = tid; c < NCOL; c += 256) {
        float mean = stats[c] * (1.f / (float)NVOX);
        float var = stats[NCOL + c] * (1.f / (float)NVOX) - mean * mean;
        float inv = rsqrtf(var + 1e-5f);
        float sc = inv * gamma[c];
        sScale[c] = sc;
        sShift[c] = beta[c] - mean * sc;
    }
    for (int i = tid; i < 192; i += 256) { int cc = i / 3, jj = i - cc * 3; sW1[0 * 192 + i] = W1_0[cc * 3 + jj]; }
    for (int i = tid; i < 192; i += 256) { int cc = i / 3, jj = i - cc * 3; sW1[1 * 192 + i] = (jj < 2) ? W1_1[cc * 2 + jj] : 0.f; }
    for (int i = tid; i < 192; i += 256) { int cc = i / 3, jj = i - cc * 3; sW1[2 * 192 + i] = (jj < 1) ? W1_2[cc] : 0.f; }
    for (int i = tid; i < 192; i += 256) { int cc = i / 3, jj = i - cc * 3; sW1[3 * 192 + i] = W1_3[cc * 3 + jj]; }
    for (int i = tid; i < 192; i += 256) { int cc = i / 3, jj = i - cc * 3; sW1[4 * 192 + i] = (jj < 2) ? W1_4[cc * 2 + jj] : 0.f; }
    if (tid == 0) {
        sB1[0] = b1_0[0]; sB1[1] = b1_0[1]; sB1[2] = b1_0[2];
        sB1[3] = b1_1[0]; sB1[4] = b1_1[1]; sB1[5] = 0.f;
        sB1[6] = b1_2[0]; sB1[7] = 0.f;    sB1[8] = 0.f;
        sB1[9] = b1_3[0]; sB1[10] = b1_3[1]; sB1[11] = b1_3[2];
        sB1[12] = b1_4[0]; sB1[13] = b1_4[1]; sB1[14] = 0.f;
    }
    __syncthreads();
    int lin = blockIdx.x * 256 + tid;     // 5 heads x 75008 row-pairs (wave-aligned)
    int h = lin / 75008;
    int rp = lin - h * 75008;
    if (rp >= 75000) return;
    int n = rp * 2;                       // rows n, n+1
    const unsigned short* hp = hbuf + n;
    float x0 = sB1[h * 3 + 0], x1 = sB1[h * 3 + 1], x2 = sB1[h * 3 + 2];
    float y0 = x0, y1 = x1, y2 = x2;
    int cbase = h * 64;
#pragma unroll 8
    for (int cc = 0; cc < 64; ++cc) {
        int c = cbase + cc;
        unsigned raw = *(const unsigned*)(hp + (size_t)c * SROW);
        float v0 = __builtin_bit_cast(float, raw << 16);
        float v1 = __builtin_bit_cast(float, raw & 0xffff0000u);
        float sc = sScale[c], sh = sShift[c];
        v0 = fmaxf(v0 * sc + sh, 0.f);
        v1 = fmaxf(v1 * sc + sh, 0.f);
        float w0 = sW1[c * 3 + 0], w1 = sW1[c * 3 + 1], w2 = sW1[c * 3 + 2];
        x0 += v0 * w0; x1 += v0 * w1; x2 += v0 * w2;
        y0 += v1 * w0; y1 += v1 * w1; y2 += v1 * w2;
    }
    if (h == 0) {
        out[n * 3 + 0] = x0; out[n * 3 + 1] = x1; out[n * 3 + 2] = x2;
        out[(n + 1) * 3 + 0] = y0; out[(n + 1) * 3 + 1] = y1; out[(n + 1) * 3 + 2] = y2;
    } else if (h == 1) {
        out[450000 + n * 2 + 0] = x0; out[450000 + n * 2 + 1] = x1;
        out[450000 + (n + 1) * 2 + 0] = y0; out[450000 + (n + 1) * 2 + 1] = y1;
    } else if (h == 2) {
        out[750000 + n] = x0; out[750000 + n + 1] = y0;
    } else if (h == 3) {
        out[900000 + n * 3 + 0] = x0; out[900000 + n * 3 + 1] = x1; out[900000 + n * 3 + 2] = x2;
        out[900000 + (n + 1) * 3 + 0] = y0; out[900000 + (n + 1) * 3 + 1] = y1; out[900000 + (n + 1) * 3 + 2] = y2;
    } else {
        out[1350000 + n * 2 + 0] = x0; out[1350000 + n * 2 + 1] = x1;
        out[1350000 + (n + 1) * 2 + 0] = y0; out[1350000 + (n + 1) * 2 + 1] = y1;
    }
}

extern "C" void kernel_launch(void* const* d_in, const int* in_sizes, int n_in,
                              void* d_out, int out_size, void* d_ws, size_t ws_size,
                              hipStream_t stream) {
    const float* features = (const float*)d_in[0];
    const int* nbr        = (const int*)d_in[1];
    const float* w3       = (const float*)d_in[2];
    const float* gamma    = (const float*)d_in[3];
    const float* beta     = (const float*)d_in[4];
    const float* W1_0 = (const float*)d_in[5];  const float* b1_0 = (const float*)d_in[6];
    const float* W1_1 = (const float*)d_in[7];  const float* b1_1 = (const float*)d_in[8];
    const float* W1_2 = (const float*)d_in[9];  const float* b1_2 = (const float*)d_in[10];
    const float* W1_3 = (const float*)d_in[11]; const float* b1_3 = (const float*)d_in[12];
    const float* W1_4 = (const float*)d_in[13]; const float* b1_4 = (const float*)d_in[14];
    float* out = (float*)d_out;

    char* ws = (char*)d_ws;
    unsigned short* featB = (unsigned short*)ws;               // (150000+1)*64 bf16
    unsigned short* Bt    = (unsigned short*)(ws + 19200128);  // 5*64*576 bf16
    float* stats          = (float*)(ws + 19568768);           // 640 f32
    unsigned short* hbuf  = (unsigned short*)(ws + 19571328);  // 320*150016 bf16

    prep_feat<<<(NVOX * 8 + 8 + 255) / 256, 256, 0, stream>>>(features, featB);
    prep_w3<<<45, 256, 0, stream>>>(w3, Bt, stats);
    gemm_kernel<<<8 * 5 * 147, 256, 0, stream>>>(featB, Bt, nbr, hbuf, stats);
    head_kernel<<<(5 * 75008) / 256, 256, 0, stream>>>(hbuf, stats, gamma, beta,
        W1_0, W1_1, W1_2, W1_3, W1_4, b1_0, b1_1, b1_2, b1_3, b1_4, out);
}

// Round 6
// 237.413 us; speedup vs baseline: 1.7423x; 1.7423x over previous
//
#include <hip/hip_runtime.h>

#define NVOX 150000
#define BM 128
#define MTILES 1172         // ceil(150000/128)
#define SROW 150016         // column stride of h buffer
#define NCOL 320

typedef __attribute__((ext_vector_type(8))) short bf16x8;
typedef __attribute__((ext_vector_type(4))) float f32x4;
typedef __attribute__((ext_vector_type(4))) unsigned short us4;

__device__ __forceinline__ unsigned short f2bf(float f) {
    unsigned u = __builtin_bit_cast(unsigned, f);
    u += 0x7fffu + ((u >> 16) & 1u);
    return (unsigned short)(u >> 16);
}

__device__ __forceinline__ void gld16(const void* g, void* l) {
    __builtin_amdgcn_global_load_lds(
        (const __attribute__((address_space(1))) unsigned int*)g,
        (__attribute__((address_space(3))) unsigned int*)l, 16, 0, 0);
}

// ---------------- prep: features f32 -> bf16, x8 vectorized (+ zero row) ----------------
__global__ void prep_feat(const float* __restrict__ src, unsigned short* __restrict__ dst) {
    int i = blockIdx.x * 256 + threadIdx.x;
    if (i < NVOX * 8) {
        const float4 a = *(const float4*)(src + (size_t)i * 8);
        const float4 b = *(const float4*)(src + (size_t)i * 8 + 4);
        us4 lo, hi;
        lo.x = f2bf(a.x); lo.y = f2bf(a.y); lo.z = f2bf(a.z); lo.w = f2bf(a.w);
        hi.x = f2bf(b.x); hi.y = f2bf(b.y); hi.z = f2bf(b.z); hi.w = f2bf(b.w);
        *(us4*)(dst + (size_t)i * 8) = lo;
        *(us4*)(dst + (size_t)i * 8 + 4) = hi;
    } else if (i < NVOX * 8 + 8) {
        us4 z; z.x = 0; z.y = 0; z.z = 0; z.w = 0;
        *(us4*)(dst + (size_t)i * 8) = z;   // zero row for invalid/pad gathers
    }
}

// ---- prep: W3[h][kk][c][o] -> fragment-packed Bf[(kk*5+h)][ks*4+nt4][lane][e] bf16 ----
// value = W3[h][kk][c = ks*32 + (lane>>4)*8 + e][o = nt4*16 + (lane&15)]
__global__ void prep_w3(const float* __restrict__ w3, unsigned short* __restrict__ bf,
                        float* __restrict__ stats) {
    __shared__ float tile[64 * 65];
    int b = blockIdx.x;            // b = h*9+kk, 45 blocks
    int tid = threadIdx.x;
    const float* src = w3 + (size_t)b * 4096;
#pragma unroll
    for (int t = 0; t < 16; ++t) {
        int lin = t * 256 + tid;   // c = lin>>6, o = lin&63  (coalesced read over o)
        tile[(lin >> 6) * 65 + (lin & 63)] = src[lin];
    }
    __syncthreads();
    int h = b / 9, kk = b - h * 9;
    unsigned short* dst = bf + (size_t)(kk * 5 + h) * 4096;
#pragma unroll
    for (int t = 0; t < 16; ++t) {
        int lin = t * 256 + tid;          // 4096 elements of this (kk,h) region
        int e = lin & 7;
        int lane = (lin >> 3) & 63;
        int t2 = lin >> 9;                // 0..7: nt4 = t2&3, ks = t2>>2
        int c = (t2 >> 2) * 32 + (lane >> 4) * 8 + e;
        int o = (t2 & 3) * 16 + (lane & 15);
        dst[lin] = f2bf(tile[c * 65 + o]);
    }
    if (b == 0) for (int j = tid; j < 2 * NCOL; j += 256) stats[j] = 0.f;
}

// ---------------- gather-GEMM: BM=128, ALL 5 heads per block (A gathered once, frags
// reused 5x). A: chunk-major global_load_lds double-buffer. B: fragment-packed coalesced
// global->reg, issued 2 heads ahead. 80 MFMA per wave per staging phase. ----------------
__global__ __launch_bounds__(256, 2)
void gemm_kernel(const unsigned short* __restrict__ featB,
                 const unsigned short* __restrict__ Bf,
                 const int* __restrict__ nbr,
                 unsigned short* __restrict__ hbuf,
                 float* __restrict__ stats) {
    __shared__ __align__(16) char smem[38400];
    constexpr int IDX_OFF = 32768;   // 9*128 int byte-offsets (4608 B)
    constexpr int SRED_OFF = 37376;  // 128 float2 (1024 B)

    int mtile = blockIdx.x;
    int m0 = mtile * BM;
    int tid = threadIdx.x;
    int w = tid >> 6, lane = tid & 63;
    int quad = lane >> 4, m16 = lane & 15;
    int mrow = (w >> 1) * 64;       // wave's 64-row half
    int colhalf = w & 1;            // wave's 32-col half (within each head's 64 cols)

    // ---- stage neighbor byte-offset table: sIdx[kk*128 + row] = srow*128 ----
    for (int lin = tid; lin < 1152; lin += 256) {
        int kkq = lin >> 7, row = lin & 127;
        int v = (m0 + row < NVOX) ? nbr[(size_t)(m0 + row) * 9 + kkq] : -1;
        *(int*)(smem + IDX_OFF + lin * 4) = ((v < 0) ? NVOX : v) * 128;
    }
    __syncthreads();

    f32x4 acc[5][4][2];
#pragma unroll
    for (int h = 0; h < 5; ++h)
#pragma unroll
        for (int mt = 0; mt < 4; ++mt)
#pragma unroll
            for (int nt = 0; nt < 2; ++nt)
                acc[h][mt][nt] = (f32x4){0.f, 0.f, 0.f, 0.f};

    const char* fb = (const char*)featB;
    const char* bfb = (const char*)Bf + colhalf * 2048 + lane * 16;

// A staging: wave w owns chunks {2w,2w+1}; buffer = kk&1; dest wave-uniform + lane*16
#define STAGE(kkx)                                                              \
    do {                                                                        \
        int o0 = *(const int*)(smem + IDX_OFF + ((kkx) * 128 + lane) * 4);      \
        int o1 = *(const int*)(smem + IDX_OFF + ((kkx) * 128 + 64 + lane) * 4); \
        char* dstS = smem + ((kkx) & 1) * 16384;                                \
        int cA = w * 2, cB = w * 2 + 1;                                         \
        gld16(fb + o0 + cA * 16, dstS + cA * 2048);                             \
        gld16(fb + o1 + cA * 16, dstS + cA * 2048 + 1024);                      \
        gld16(fb + o0 + cB * 16, dstS + cB * 2048);                             \
        gld16(fb + o1 + cB * 16, dstS + cB * 2048 + 1024);                      \
    } while (0)

// B fragment load for head h of neighbor kk (4x 1KB coalesced wave streams)
#define LDB(dst, kkx, h)                                                        \
    do {                                                                        \
        _Pragma("unroll")                                                       \
        for (int ks = 0; ks < 2; ++ks)                                          \
            _Pragma("unroll")                                                   \
            for (int nt = 0; nt < 2; ++nt)                                      \
                dst[ks * 2 + nt] = *(const bf16x8*)(bfb +                       \
                    ((kkx) * 5 + (h)) * 8192 + ks * 4096 + nt * 1024);          \
    } while (0)

// 16 MFMAs for head h using persistent A frags + B buffer
#define MFH(h, B)                                                               \
    do {                                                                        \
        _Pragma("unroll")                                                       \
        for (int ks = 0; ks < 2; ++ks)                                          \
            _Pragma("unroll")                                                   \
            for (int mt = 0; mt < 4; ++mt)                                      \
                _Pragma("unroll")                                               \
                for (int nt = 0; nt < 2; ++nt)                                  \
                    acc[h][mt][nt] = __builtin_amdgcn_mfma_f32_16x16x32_bf16(   \
                        af[ks][mt], B[ks * 2 + nt], acc[h][mt][nt], 0, 0, 0);   \
    } while (0)

    STAGE(0);
    for (int kk = 0; kk < 9; ++kk) {
        __syncthreads();   // buf[kk&1] staged (vmcnt drained per wave) + prev reads done
        const char* cur = smem + (kk & 1) * 16384;
        bf16x8 af[2][4];
#pragma unroll
        for (int ks = 0; ks < 2; ++ks)
#pragma unroll
            for (int mt = 0; mt < 4; ++mt)
                af[ks][mt] = *(const bf16x8*)(cur + (ks * 4 + quad) * 2048 +
                                              (mrow + mt * 16 + m16) * 16);
        bf16x8 ba[4], bb[4];
        LDB(ba, kk, 0);
        LDB(bb, kk, 1);
        if (kk < 8) STAGE(kk + 1);   // prefetch: covered by the 80 MFMAs below
        MFH(0, ba); LDB(ba, kk, 2);
        MFH(1, bb); LDB(bb, kk, 3);
        MFH(2, ba); LDB(ba, kk, 4);
        MFH(3, bb);
        MFH(4, ba);
    }
    __syncthreads();   // K-loop LDS dead; safe to alias for epilogue
#undef STAGE
#undef LDB
#undef MFH

    // ---- epilogue: per head: LDS transpose -> coalesced 256B-run stores + BN stats ----
    unsigned short* sOut = (unsigned short*)smem;     // 64 cols x 136 ushorts
    float2* sRed = (float2*)(smem + SRED_OFF);
#pragma unroll
    for (int h = 0; h < 5; ++h) {
        float s[2], ss[2];
#pragma unroll
        for (int nt = 0; nt < 2; ++nt) {
            int col = colhalf * 32 + nt * 16 + m16;
            float a = 0.f, b = 0.f;
#pragma unroll
            for (int mt = 0; mt < 4; ++mt) {
                int row = mrow + mt * 16 + quad * 4;
                f32x4 v = acc[h][mt][nt];
                unsigned lo = (unsigned)f2bf(v.x) | ((unsigned)f2bf(v.y) << 16);
                unsigned hi = (unsigned)f2bf(v.z) | ((unsigned)f2bf(v.w) << 16);
                uint2 pk; pk.x = lo; pk.y = hi;
                *(uint2*)(sOut + col * 136 + row) = pk;
                a += v.x + v.y + v.z + v.w;
                b += v.x * v.x + v.y * v.y + v.z * v.z + v.w * v.w;
            }
            s[nt] = a; ss[nt] = b;
            s[nt] += __shfl_xor(s[nt], 16); s[nt] += __shfl_xor(s[nt], 32);
            ss[nt] += __shfl_xor(ss[nt], 16); ss[nt] += __shfl_xor(ss[nt], 32);
        }
        if (quad == 0) {
#pragma unroll
            for (int nt = 0; nt < 2; ++nt) {
                float2 p; p.x = s[nt]; p.y = ss[nt];
                sRed[(w * 2 + nt) * 16 + m16] = p;
            }
        }
        __syncthreads();   // sOut + sRed complete
#pragma unroll
        for (int it = 0; it < 8; ++it) {
            int col = it * 8 + (tid >> 5);
            int l32 = tid & 31;
            uint2 v = *(const uint2*)(sOut + col * 136 + l32 * 4);
            *(uint2*)(hbuf + (size_t)(h * 64 + col) * SROW + m0 + l32 * 4) = v;
        }
        if (tid < 64) {
            int ch = tid >> 5, nt = (tid >> 4) & 1, mc = tid & 15;
            float2 p0 = sRed[((ch) * 2 + nt) * 16 + mc];
            float2 p1 = sRed[((ch + 2) * 2 + nt) * 16 + mc];
            atomicAdd(&stats[h * 64 + tid], p0.x + p1.x);
            atomicAdd(&stats[NCOL + h * 64 + tid], p0.y + p1.y);
        }
        __syncthreads();   // sOut/sRed reusable for next head
    }
}

// ------- pass 2: BN + ReLU + 1x1 conv; thread = (row-pair, head), h wave-uniform -------
__global__ void head_kernel(const unsigned short* __restrict__ hbuf,
                            const float* __restrict__ stats,
                            const float* __restrict__ gamma, const float* __restrict__ beta,
                            const float* __restrict__ W1_0, const float* __restrict__ W1_1,
                            const float* __restrict__ W1_2, const float* __restrict__ W1_3,
                            const float* __restrict__ W1_4,
                            const float* __restrict__ b1_0, const float* __restrict__ b1_1,
                            const float* __restrict__ b1_2, const float* __restrict__ b1_3,
                            const float* __restrict__ b1_4,
                            float* __restrict__ out) {
    __shared__ float sScale[NCOL], sShift[NCOL], sW1[NCOL * 3], sB1[16];
    int tid = threadIdx.x;
    for (int c = tid; c < NCOL; c += 256) {
        float mean = stats[c] * (1.f / (float)NVOX);
        float var = stats[NCOL + c] * (1.f / (float)NVOX) - mean * mean;
        float inv = rsqrtf(var + 1e-5f);
        float sc = inv * gamma[c];
        sScale[c] = sc;
        sShift[c] = beta[c] - mean * sc;
    }
    for (int i = tid; i < 192; i += 256) { int cc = i / 3, jj = i - cc * 3; sW1[0 * 192 + i] = W1_0[cc * 3 + jj]; }
    for (int i = tid; i < 192; i += 256) { int cc = i / 3, jj = i - cc * 3; sW1[1 * 192 + i] = (jj < 2) ? W1_1[cc * 2 + jj] : 0.f; }
    for (int i = tid; i < 192; i += 256) { int cc = i / 3, jj = i - cc * 3; sW1[2 * 192 + i] = (jj < 1) ? W1_2[cc] : 0.f; }
    for (int i = tid; i < 192; i += 256) { int cc = i / 3, jj = i - cc * 3; sW1[3 * 192 + i] = W1_3[cc * 3 + jj]; }
    for (int i = tid; i < 192; i += 256) { int cc = i / 3, jj = i - cc * 3; sW1[4 * 192 + i] = (jj < 2) ? W1_4[cc * 2 + jj] : 0.f; }
    if (tid == 0) {
        sB1[0] = b1_0[0]; sB1[1] = b1_0[1]; sB1[2] = b1_0[2];
        sB1[3] = b1_1[0]; sB1[4] = b1_1[1]; sB1[5] = 0.f;
        sB1[6] = b1_2[0]; sB1[7] = 0.f;    sB1[8] = 0.f;
        sB1[9] = b1_3[0]; sB1[10] = b1_3[1]; sB1[11] = b1_3[2];
        sB1[12] = b1_4[0]; sB1[13] = b1_4[1]; sB1[14] = 0.f;
    }
    __syncthreads();
    int lin = blockIdx.x * 256 + tid;     // 5 heads x 75008 row-pairs (wave-aligned)
    int h = lin / 75008;
    int rp = lin - h * 75008;
    if (rp >= 75000) return;
    int n = rp * 2;                       // rows n, n+1
    const unsigned short* hp = hbuf + n;
    float x0 = sB1[h * 3 + 0], x1 = sB1[h * 3 + 1], x2 = sB1[h * 3 + 2];
    float y0 = x0, y1 = x1, y2 = x2;
    int cbase = h * 64;
#pragma unroll 16
    for (int cc = 0; cc < 64; ++cc) {
        int c = cbase + cc;
        unsigned raw = *(const unsigned*)(hp + (size_t)c * SROW);
        float v0 = __builtin_bit_cast(float, raw << 16);
        float v1 = __builtin_bit_cast(float, raw & 0xffff0000u);
        float sc = sScale[c], sh = sShift[c];
        v0 = fmaxf(v0 * sc + sh, 0.f);
        v1 = fmaxf(v1 * sc + sh, 0.f);
        float w0 = sW1[c * 3 + 0], w1 = sW1[c * 3 + 1], w2 = sW1[c * 3 + 2];
        x0 += v0 * w0; x1 += v0 * w1; x2 += v0 * w2;
        y0 += v1 * w0; y1 += v1 * w1; y2 += v1 * w2;
    }
    if (h == 0) {
        out[n * 3 + 0] = x0; out[n * 3 + 1] = x1; out[n * 3 + 2] = x2;
        out[(n + 1) * 3 + 0] = y0; out[(n + 1) * 3 + 1] = y1; out[(n + 1) * 3 + 2] = y2;
    } else if (h == 1) {
        out[450000 + n * 2 + 0] = x0; out[450000 + n * 2 + 1] = x1;
        out[450000 + (n + 1) * 2 + 0] = y0; out[450000 + (n + 1) * 2 + 1] = y1;
    } else if (h == 2) {
        out[750000 + n] = x0; out[750000 + n + 1] = y0;
    } else if (h == 3) {
        out[900000 + n * 3 + 0] = x0; out[900000 + n * 3 + 1] = x1; out[900000 + n * 3 + 2] = x2;
        out[900000 + (n + 1) * 3 + 0] = y0; out[900000 + (n + 1) * 3 + 1] = y1; out[900000 + (n + 1) * 3 + 2] = y2;
    } else {
        out[1350000 + n * 2 + 0] = x0; out[1350000 + n * 2 + 1] = x1;
        out[1350000 + (n + 1) * 2 + 0] = y0; out[1350000 + (n + 1) * 2 + 1] = y1;
    }
}

extern "C" void kernel_launch(void* const* d_in, const int* in_sizes, int n_in,
                              void* d_out, int out_size, void* d_ws, size_t ws_size,
                              hipStream_t stream) {
    const float* features = (const float*)d_in[0];
    const int* nbr        = (const int*)d_in[1];
    const float* w3       = (const float*)d_in[2];
    const float* gamma    = (const float*)d_in[3];
    const float* beta     = (const float*)d_in[4];
    const float* W1_0 = (const float*)d_in[5];  const float* b1_0 = (const float*)d_in[6];
    const float* W1_1 = (const float*)d_in[7];  const float* b1_1 = (const float*)d_in[8];
    const float* W1_2 = (const float*)d_in[9];  const float* b1_2 = (const float*)d_in[10];
    const float* W1_3 = (const float*)d_in[11]; const float* b1_3 = (const float*)d_in[12];
    const float* W1_4 = (const float*)d_in[13]; const float* b1_4 = (const float*)d_in[14];
    float* out = (float*)d_out;

    char* ws = (char*)d_ws;
    unsigned short* featB = (unsigned short*)ws;               // (150000+1)*64 bf16
    unsigned short* Bf    = (unsigned short*)(ws + 19200128);  // 45*4096 bf16 = 368,640 B
    float* stats          = (float*)(ws + 19568768);           // 640 f32
    unsigned short* hbuf  = (unsigned short*)(ws + 19571328);  // 320*150016 bf16

    prep_feat<<<(NVOX * 8 + 8 + 255) / 256, 256, 0, stream>>>(features, featB);
    prep_w3<<<45, 256, 0, stream>>>(w3, Bf, stats);
    gemm_kernel<<<MTILES, 256, 0, stream>>>(featB, Bf, nbr, hbuf, stats);
    head_kernel<<<(5 * 75008) / 256, 256, 0, stream>>>(hbuf, stats, gamma, beta,
        W1_0, W1_1, W1_2, W1_3, W1_4, b1_0, b1_1, b1_2, b1_3, b1_4, out);
}